// Round 8
// baseline (380.486 us; speedup 1.0000x reference)
//
#include <hip/hip_runtime.h>
#include <hip/hip_bf16.h>

// Problem constants (B=2, N=2048, DIM=1024, H=16, HD=64, BS=64, M=32)
#define BB 2
#define NN 2048
#define DIMD 1024
#define HH 16
#define HD64 64
#define MB 32
#define SCALE_F 0.125f   // HD^-0.5

typedef __attribute__((ext_vector_type(8))) short bf16x8;
typedef __attribute__((ext_vector_type(4))) float f32x4;
typedef _Float16 f16;
typedef __attribute__((ext_vector_type(8))) _Float16 f16x8;

#define LSTR 72   // padded LDS row stride (f16): 144B rows, 16B-aligned

__device__ __forceinline__ unsigned short bf16_hi(float f) {
    return __builtin_bit_cast(unsigned short, __float2bfloat16(f));
}
__device__ __forceinline__ float bf16_val(unsigned short u) {
    return __bfloat162float(__builtin_bit_cast(__hip_bfloat16, u));
}
__device__ __forceinline__ void async_copy16(const void* g, void* l) {
    __builtin_amdgcn_global_load_lds((const __attribute__((address_space(1))) void*)g,
                                     (__attribute__((address_space(3))) void*)l, 16, 0, 0);
}

// ===========================================================================
// FAST PATH
// ===========================================================================

// Split fp32 [rows][1024] -> bf16 hi|lo [rows][2048]
__global__ __launch_bounds__(256) void split_bf16_kernel(
    const float* __restrict__ src, short* __restrict__ dst, int total4)
{
    int idx = blockIdx.x * 256 + threadIdx.x;
    if (idx >= total4) return;
    int e = idx * 4;
    int r = e >> 10, c = e & 1023;
    float4 v = *(const float4*)(src + e);
    unsigned short h0 = bf16_hi(v.x), h1 = bf16_hi(v.y), h2 = bf16_hi(v.z), h3 = bf16_hi(v.w);
    unsigned short l0 = bf16_hi(v.x - bf16_val(h0));
    unsigned short l1 = bf16_hi(v.y - bf16_val(h1));
    unsigned short l2 = bf16_hi(v.z - bf16_val(h2));
    unsigned short l3 = bf16_hi(v.w - bf16_val(h3));
    size_t base = (size_t)r * 2048 + c;
    *(ushort4*)(dst + base)        = make_ushort4(h0, h1, h2, h3);
    *(ushort4*)(dst + base + 1024) = make_ushort4(l0, l1, l2, l3);
}

// QKV GEMM via bf16x3 MFMA. Round-6 epilogue (fp32 q/k/v, q pre-scaled).
// NEW: permuted staging lanes -> linear (conflict-free) MFMA frag reads.
// Staging: lane l fetches global row chunk*16+(l&15), k-offset (l>>4)*8;
// LDS dest is forced base+l*16B, so frag addr for (row=lane&15, quad=lane>>4)
// is exactly base + lane*16B — sequential banks, zero conflicts.
__global__ __launch_bounds__(256) void qkv_mfma_kernel(
    const short* __restrict__ A, const short* __restrict__ W,
    float* __restrict__ qf, float* __restrict__ kf, float* __restrict__ vf)
{
    __shared__ short As[128 * 32];
    __shared__ short Bs[128 * 32];
    const int tid = threadIdx.x;
    const int lane = tid & 63;
    const int wave = tid >> 6;
    const int row0 = blockIdx.y * 128;
    const int col0 = blockIdx.x * 128;
    const int wm = wave & 1, wn = wave >> 1;

    f32x4 acc[4][4];
    const f32x4 zero = {0.f, 0.f, 0.f, 0.f};
    #pragma unroll
    for (int i = 0; i < 4; ++i)
        #pragma unroll
        for (int j = 0; j < 4; ++j) acc[i][j] = zero;

    const int ldr = lane & 15;           // global row within 16-row chunk
    const int lko = (lane >> 4) * 8;     // k-offset (8 shorts = 16B)

    for (int kt = 0; kt < 96; ++kt) {
        const int seg = kt >> 5;
        const int kk = (kt & 31) << 5;
        const int ka0 = kk + (seg == 2 ? 1024 : 0);
        const int kw0 = kk + (seg == 1 ? 1024 : 0);
        #pragma unroll
        for (int i = 0; i < 2; ++i) {
            const int chunk = wave * 2 + i;          // 0..7 (16 rows each)
            const short* gA = A + (size_t)(row0 + chunk * 16 + ldr) * 2048 + ka0 + lko;
            const short* gB = W + (size_t)(col0 + chunk * 16 + ldr) * 2048 + kw0 + lko;
            async_copy16(gA, (char*)As + chunk * 1024);
            async_copy16(gB, (char*)Bs + chunk * 1024);
        }
        __syncthreads();
        bf16x8 af[4], bfr[4];
        #pragma unroll
        for (int mi = 0; mi < 4; ++mi)
            af[mi] = *(const bf16x8*)(As + (wm * 4 + mi) * 512 + lane * 8);
        #pragma unroll
        for (int ni = 0; ni < 4; ++ni)
            bfr[ni] = *(const bf16x8*)(Bs + (wn * 4 + ni) * 512 + lane * 8);
        #pragma unroll
        for (int mi = 0; mi < 4; ++mi)
            #pragma unroll
            for (int ni = 0; ni < 4; ++ni)
                acc[mi][ni] = __builtin_amdgcn_mfma_f32_16x16x32_bf16(af[mi], bfr[ni], acc[mi][ni], 0, 0, 0);
        __syncthreads();
    }

    // epilogue (round-6 proven): scatter fp32 into q/k/v [bh][n][64], q scaled
    #pragma unroll
    for (int ni = 0; ni < 4; ++ni) {
        int gc = col0 + wn * 64 + ni * 16 + (lane & 15);
        int tsel = gc >> 10;
        int h = (gc >> 6) & 15;
        int d = gc & 63;
        float* dst = (tsel == 0) ? qf : (tsel == 1) ? kf : vf;
        float sc = (tsel == 0) ? SCALE_F : 1.0f;
        #pragma unroll
        for (int mi = 0; mi < 4; ++mi) {
            int gr0 = row0 + wm * 64 + mi * 16 + (lane >> 4) * 4;
            #pragma unroll
            for (int r = 0; r < 4; ++r) {
                int gr = gr0 + r;
                int bb = gr >> 11, n = gr & 2047;
                dst[(((size_t)((bb << 4) + h)) * NN + n) * HD64 + d] = acc[mi][ni][r] * sc;
            }
        }
    }
}

// In-place fp32 [bh][n][64] -> f16 hi|lo [bh][n][128] (same bytes per row).
// LDS-staged per block: all reads of the block's region complete before any
// write (barrier), so in-place is race-free. 64 rows (16 KB) per block.
__global__ __launch_bounds__(256) void split_qk_inplace_kernel(
    float* __restrict__ qbuf, float* __restrict__ kbuf)
{
    __shared__ float tile[4096];
    float* buf = (blockIdx.x < 1024) ? qbuf : kbuf;
    const int row0 = (blockIdx.x & 1023) * 64;
    const int t = threadIdx.x;
    const float* src = buf + (size_t)row0 * 64;
    #pragma unroll
    for (int i = 0; i < 4; ++i)
        *(float4*)(tile + t * 4 + i * 1024) = *(const float4*)(src + t * 4 + i * 1024);
    __syncthreads();
    const int r = t >> 2, d0 = (t & 3) * 16;
    f16x8 hv0, hv1, lv0, lv1;
    #pragma unroll
    for (int j = 0; j < 8; ++j) {
        float v = tile[r * 64 + d0 + j];
        f16 hh = (f16)v;
        hv0[j] = hh; lv0[j] = (f16)(v - (float)hh);
    }
    #pragma unroll
    for (int j = 0; j < 8; ++j) {
        float v = tile[r * 64 + d0 + 8 + j];
        f16 hh = (f16)v;
        hv1[j] = hh; lv1[j] = (f16)(v - (float)hh);
    }
    f16* dst = (f16*)buf + ((size_t)(row0 + r)) * 128;
    *(f16x8*)(dst + d0)          = hv0;
    *(f16x8*)(dst + d0 + 8)      = hv1;
    *(f16x8*)(dst + 64 + d0)     = lv0;
    *(f16x8*)(dst + 64 + d0 + 8) = lv1;
}

// Transpose v: vf fp32 [bh][n][64] -> vt f16 [bh][d][2048]. 1024 blocks.
__global__ __launch_bounds__(256) void transpose_vt_kernel(
    const float* __restrict__ vf, f16* __restrict__ vt)
{
    __shared__ float tile[64][65];
    const int nb = blockIdx.x & 31, bh = blockIdx.x >> 5;
    const int t = threadIdx.x;
    {
        const int r = t >> 2, c0 = (t & 3) * 16;
        const float* src = vf + ((size_t)bh * NN + nb * 64 + r) * HD64 + c0;
        #pragma unroll
        for (int j = 0; j < 16; j += 4) {
            float4 v4 = *(const float4*)(src + j);
            tile[r][c0 + j]     = v4.x;
            tile[r][c0 + j + 1] = v4.y;
            tile[r][c0 + j + 2] = v4.z;
            tile[r][c0 + j + 3] = v4.w;
        }
    }
    __syncthreads();
    {
        const int d = t >> 2, n0 = (t & 3) * 16;
        f16x8 o0, o1;
        #pragma unroll
        for (int j = 0; j < 8; ++j) o0[j] = (f16)tile[n0 + j][d];
        #pragma unroll
        for (int j = 0; j < 8; ++j) o1[j] = (f16)tile[n0 + 8 + j][d];
        f16* dst = vt + ((size_t)bh * HD64 + d) * NN + nb * 64 + n0;
        *(f16x8*)(dst)     = o0;
        *(f16x8*)(dst + 8) = o1;
    }
}

// Proj GEMM via bf16x3 MFMA + bias. Same conflict-free staging permutation.
__global__ __launch_bounds__(256) void proj_mfma_kernel(
    const short* __restrict__ A, const short* __restrict__ W,
    const float* __restrict__ bias, float* __restrict__ out)
{
    __shared__ short As[128 * 32];
    __shared__ short Bs[64 * 32];
    const int tid = threadIdx.x;
    const int lane = tid & 63;
    const int wave = tid >> 6;
    const int row0 = blockIdx.y * 128;
    const int col0 = blockIdx.x * 64;

    f32x4 acc[2][4];
    const f32x4 zero = {0.f, 0.f, 0.f, 0.f};
    #pragma unroll
    for (int i = 0; i < 2; ++i)
        #pragma unroll
        for (int j = 0; j < 4; ++j) acc[i][j] = zero;

    const int ldr = lane & 15;
    const int lko = (lane >> 4) * 8;

    for (int kt = 0; kt < 96; ++kt) {
        const int seg = kt >> 5;
        const int kk = (kt & 31) << 5;
        const int ka0 = kk + (seg == 2 ? 1024 : 0);
        const int kw0 = kk + (seg == 1 ? 1024 : 0);
        #pragma unroll
        for (int i = 0; i < 2; ++i) {
            const int chunk = wave * 2 + i;
            const short* gA = A + (size_t)(row0 + chunk * 16 + ldr) * 2048 + ka0 + lko;
            async_copy16(gA, (char*)As + chunk * 1024);
        }
        {
            const short* gB = W + (size_t)(col0 + wave * 16 + ldr) * 2048 + kw0 + lko;
            async_copy16(gB, (char*)Bs + wave * 1024);
        }
        __syncthreads();
        bf16x8 af[2], bfr[4];
        #pragma unroll
        for (int mi = 0; mi < 2; ++mi)
            af[mi] = *(const bf16x8*)(As + (wave * 2 + mi) * 512 + lane * 8);
        #pragma unroll
        for (int ni = 0; ni < 4; ++ni)
            bfr[ni] = *(const bf16x8*)(Bs + ni * 512 + lane * 8);
        #pragma unroll
        for (int mi = 0; mi < 2; ++mi)
            #pragma unroll
            for (int ni = 0; ni < 4; ++ni)
                acc[mi][ni] = __builtin_amdgcn_mfma_f32_16x16x32_bf16(af[mi], bfr[ni], acc[mi][ni], 0, 0, 0);
        __syncthreads();
    }

    #pragma unroll
    for (int ni = 0; ni < 4; ++ni) {
        int gc = col0 + ni * 16 + (lane & 15);
        float bv = bias[gc];
        #pragma unroll
        for (int mi = 0; mi < 2; ++mi) {
            int gr0 = row0 + wave * 32 + mi * 16 + (lane >> 4) * 4;
            #pragma unroll
            for (int r = 0; r < 4; ++r)
                out[(size_t)(gr0 + r) * 1024 + gc] = acc[mi][ni][r] + bv;
        }
    }
}

// ---------------------------------------------------------------------------
// Sparse block attention on MFMA (round-7, proven). 256 thr = 4 waves/(bh,m).
// Inputs pre-split: qs/ks f16 hi|lo [bh][n][128] (q pre-scaled), vt f16 [bh][d][n].
// ---------------------------------------------------------------------------
__global__ __launch_bounds__(256) void sparse_attn_mfma_kernel(
    const f16* __restrict__ qs, const f16* __restrict__ ks,
    const f16* __restrict__ vt, const unsigned int* __restrict__ maskbits,
    short* __restrict__ aout)
{
    __shared__ f16 Qh[64 * LSTR], Ql[64 * LSTR];
    __shared__ f16 Kh[64 * LSTR], Kl[64 * LSTR];
    __shared__ f16 Vt[64 * LSTR];
    __shared__ f16 Pb[64 * LSTR];

    const int m  = blockIdx.x & 31;
    const int bh = blockIdx.x >> 5;
    const int b  = bh >> 4, h = bh & 15;
    const int tid = threadIdx.x;
    const int lane = tid & 63;
    const int wave = tid >> 6;
    const f32x4 zero = {0.f, 0.f, 0.f, 0.f};

    {
        const int r = tid >> 2, c0 = (tid & 3) * 16;
        const f16* src = qs + ((size_t)bh * NN + m * 64 + r) * 128 + c0;
        *(f16x8*)(Qh + r * LSTR + c0)     = *(const f16x8*)(src);
        *(f16x8*)(Qh + r * LSTR + c0 + 8) = *(const f16x8*)(src + 8);
        *(f16x8*)(Ql + r * LSTR + c0)     = *(const f16x8*)(src + 64);
        *(f16x8*)(Ql + r * LSTR + c0 + 8) = *(const f16x8*)(src + 72);
    }
    __syncthreads();

    const unsigned int mask = maskbits[bh * 32 + m];
    f32x4 s_acc[4], o_acc[4];
    float macc[4], lacc[4];
    #pragma unroll
    for (int r = 0; r < 4; ++r) { macc[r] = -INFINITY; lacc[r] = 0.f; }
    #pragma unroll
    for (int t = 0; t < 4; ++t) o_acc[t] = zero;

    const int arow = wave * 16 + (lane & 15);
    const int kofs = (lane >> 4) * 8;

    for (int nb = 0; nb < 32; ++nb) {
        if (!((mask >> nb) & 1u)) continue;
        __syncthreads();

        {
            const int r = tid >> 2, c0 = (tid & 3) * 16;
            const f16* srck = ks + ((size_t)bh * NN + nb * 64 + r) * 128 + c0;
            *(f16x8*)(Kh + r * LSTR + c0)     = *(const f16x8*)(srck);
            *(f16x8*)(Kh + r * LSTR + c0 + 8) = *(const f16x8*)(srck + 8);
            *(f16x8*)(Kl + r * LSTR + c0)     = *(const f16x8*)(srck + 64);
            *(f16x8*)(Kl + r * LSTR + c0 + 8) = *(const f16x8*)(srck + 72);
            const f16* srcv = vt + ((size_t)bh * HD64 + r) * NN + nb * 64 + c0;
            *(f16x8*)(Vt + r * LSTR + c0)     = *(const f16x8*)(srcv);
            *(f16x8*)(Vt + r * LSTR + c0 + 8) = *(const f16x8*)(srcv + 8);
        }
        __syncthreads();

        #pragma unroll
        for (int t = 0; t < 4; ++t) s_acc[t] = zero;
        #pragma unroll
        for (int c = 0; c < 2; ++c) {
            f16x8 ah = *(const f16x8*)(Qh + arow * LSTR + c * 32 + kofs);
            f16x8 al = *(const f16x8*)(Ql + arow * LSTR + c * 32 + kofs);
            #pragma unroll
            for (int t = 0; t < 4; ++t) {
                f16x8 bh_ = *(const f16x8*)(Kh + (t * 16 + (lane & 15)) * LSTR + c * 32 + kofs);
                f16x8 bl_ = *(const f16x8*)(Kl + (t * 16 + (lane & 15)) * LSTR + c * 32 + kofs);
                s_acc[t] = __builtin_amdgcn_mfma_f32_16x16x32_f16(ah, bh_, s_acc[t], 0, 0, 0);
                s_acc[t] = __builtin_amdgcn_mfma_f32_16x16x32_f16(ah, bl_, s_acc[t], 0, 0, 0);
                s_acc[t] = __builtin_amdgcn_mfma_f32_16x16x32_f16(al, bh_, s_acc[t], 0, 0, 0);
            }
        }

        float alpha[4], psum[4];
        #pragma unroll
        for (int r = 0; r < 4; ++r) {
            float v0 = fmaxf(fmaxf(s_acc[0][r], s_acc[1][r]), fmaxf(s_acc[2][r], s_acc[3][r]));
            #pragma unroll
            for (int off = 1; off < 16; off <<= 1)
                v0 = fmaxf(v0, __shfl_xor(v0, off));
            float mnew = fmaxf(macc[r], v0);
            alpha[r] = expf(macc[r] - mnew);
            macc[r] = mnew;
            psum[r] = 0.f;
        }
        #pragma unroll
        for (int t = 0; t < 4; ++t) {
            #pragma unroll
            for (int r = 0; r < 4; ++r) {
                float p = expf(s_acc[t][r] - macc[r]);
                psum[r] += p;
                Pb[(wave * 16 + (lane >> 4) * 4 + r) * LSTR + t * 16 + (lane & 15)] = (f16)p;
            }
        }
        #pragma unroll
        for (int r = 0; r < 4; ++r) {
            float v0 = psum[r];
            #pragma unroll
            for (int off = 1; off < 16; off <<= 1) v0 += __shfl_xor(v0, off);
            lacc[r] = lacc[r] * alpha[r] + v0;
            #pragma unroll
            for (int t = 0; t < 4; ++t) o_acc[t][r] *= alpha[r];
        }
        __syncthreads();

        #pragma unroll
        for (int c = 0; c < 2; ++c) {
            f16x8 af = *(const f16x8*)(Pb + arow * LSTR + c * 32 + kofs);
            #pragma unroll
            for (int t = 0; t < 4; ++t) {
                f16x8 bf = *(const f16x8*)(Vt + (t * 16 + (lane & 15)) * LSTR + c * 32 + kofs);
                o_acc[t] = __builtin_amdgcn_mfma_f32_16x16x32_f16(af, bf, o_acc[t], 0, 0, 0);
            }
        }
    }

    float inv[4];
    #pragma unroll
    for (int r = 0; r < 4; ++r) inv[r] = (lacc[r] > 0.f) ? (1.f / lacc[r]) : 0.f;
    #pragma unroll
    for (int t = 0; t < 4; ++t) {
        int gc = h * 64 + t * 16 + (lane & 15);
        #pragma unroll
        for (int r = 0; r < 4; ++r) {
            int grow = b * NN + m * 64 + wave * 16 + (lane >> 4) * 4 + r;
            float v = o_acc[t][r] * inv[r];
            unsigned short hh = bf16_hi(v);
            unsigned short ll = bf16_hi(v - bf16_val(hh));
            aout[(size_t)grow * 2048 + gc] = (short)hh;
            aout[(size_t)grow * 2048 + 1024 + gc] = (short)ll;
        }
    }
}

// ===========================================================================
// SHARED / FALLBACK KERNELS
// ===========================================================================

__global__ __launch_bounds__(256) void block_mean_kernel(
    const float* __restrict__ qf, const float* __restrict__ kf,
    float* __restrict__ qbf, float* __restrict__ kbf)
{
    int idx = blockIdx.x * 256 + threadIdx.x;
    const float* src = (idx < 65536) ? qf : kf;
    float* dst       = (idx < 65536) ? qbf : kbf;
    int e = idx & 65535;
    int d = e & 63;
    int r = e >> 6;
    size_t base = (size_t)r * 4096 + d;
    float s = 0.f;
    #pragma unroll
    for (int i = 0; i < 64; ++i) s += src[base + (size_t)i * 64];
    dst[e] = s * (1.f / 64.f);
}

__global__ __launch_bounds__(128) void block_scores_kernel(
    const float* __restrict__ qbf, const float* __restrict__ kbf,
    unsigned int* __restrict__ maskbits, float scale)
{
    __shared__ float qs_[32][64];
    __shared__ float ks_[32][64];
    __shared__ float cb[32][32];
    const int bh = blockIdx.x;
    const int tid = threadIdx.x;

    #pragma unroll
    for (int i = 0; i < 16; ++i) {
        int e = tid + i * 128;
        qs_[e >> 6][e & 63] = qbf[(size_t)bh * 2048 + e];
        ks_[e >> 6][e & 63] = kbf[(size_t)bh * 2048 + e];
    }
    __syncthreads();

    #pragma unroll
    for (int i = 0; i < 8; ++i) {
        int idx = tid + i * 128;
        int r = idx >> 5, c = idx & 31;
        float s = 0.f;
        #pragma unroll
        for (int d = 0; d < 64; ++d) s += qs_[r][d] * ks_[c][d];
        cb[r][c] = s * scale;
    }
    __syncthreads();

    if (tid < 32) {
        float m1 = -INFINITY, m2 = -INFINITY;
        for (int n = 0; n < 32; ++n) {
            float v = cb[tid][n];
            if (v > m1) { m2 = m1; m1 = v; }
            else if (v > m2) { m2 = v; }
        }
        unsigned int bits = 1u << tid;
        for (int n = 0; n < 32; ++n)
            if (cb[tid][n] >= m2) bits |= 1u << n;
        maskbits[bh * 32 + tid] = bits;
    }
}

__global__ __launch_bounds__(256) void qkv_gemm_fb(
    const float* __restrict__ x, const float* __restrict__ w,
    float* __restrict__ qf, float* __restrict__ kf, float* __restrict__ vf)
{
    __shared__ float As[64][33];
    __shared__ float Bs[64][33];
    const int tid = threadIdx.x;
    const int row0 = blockIdx.y * 64;
    const int col0 = blockIdx.x * 64;
    const int ty = tid >> 4, tx = tid & 15;

    float acc[4][4] = {};
    for (int k0 = 0; k0 < 1024; k0 += 32) {
        #pragma unroll
        for (int i = 0; i < 8; ++i) {
            int e = tid + i * 256;
            int r = e >> 5, c = e & 31;
            As[r][c] = x[(size_t)(row0 + r) * 1024 + k0 + c];
            Bs[r][c] = w[(size_t)(col0 + r) * 1024 + k0 + c];
        }
        __syncthreads();
        #pragma unroll
        for (int kk = 0; kk < 32; ++kk) {
            float a[4], b[4];
            #pragma unroll
            for (int i = 0; i < 4; ++i) a[i] = As[ty * 4 + i][kk];
            #pragma unroll
            for (int j = 0; j < 4; ++j) b[j] = Bs[tx * 4 + j][kk];
            #pragma unroll
            for (int i = 0; i < 4; ++i)
                #pragma unroll
                for (int j = 0; j < 4; ++j)
                    acc[i][j] += a[i] * b[j];
        }
        __syncthreads();
    }

    const int tsel = col0 >> 10;
    const int h    = (col0 & 1023) >> 6;
    float* dstbuf = (tsel == 0) ? qf : (tsel == 1) ? kf : vf;
    #pragma unroll
    for (int i = 0; i < 4; ++i) {
        int row = row0 + ty * 4 + i;
        int b   = row >> 11, n = row & 2047;
        size_t rb = ((size_t)(b * HH + h) * NN + n) * HD64;
        #pragma unroll
        for (int j = 0; j < 4; ++j)
            dstbuf[rb + tx * 4 + j] = acc[i][j];
    }
}

__global__ __launch_bounds__(256) void proj_gemm_fb(
    const float* __restrict__ attn, const float* __restrict__ w,
    const float* __restrict__ bias, float* __restrict__ out)
{
    __shared__ float As[64][33];
    __shared__ float Bs[64][33];
    const int tid = threadIdx.x;
    const int row0 = blockIdx.y * 64;
    const int col0 = blockIdx.x * 64;
    const int ty = tid >> 4, tx = tid & 15;

    float acc[4][4] = {};
    for (int k0 = 0; k0 < 1024; k0 += 32) {
        #pragma unroll
        for (int i = 0; i < 8; ++i) {
            int e = tid + i * 256;
            int r = e >> 5, c = e & 31;
            As[r][c] = attn[(size_t)(row0 + r) * 1024 + k0 + c];
            Bs[r][c] = w[(size_t)(col0 + r) * 1024 + k0 + c];
        }
        __syncthreads();
        #pragma unroll
        for (int kk = 0; kk < 32; ++kk) {
            float a[4], b[4];
            #pragma unroll
            for (int i = 0; i < 4; ++i) a[i] = As[ty * 4 + i][kk];
            #pragma unroll
            for (int j = 0; j < 4; ++j) b[j] = Bs[tx * 4 + j][kk];
            #pragma unroll
            for (int i = 0; i < 4; ++i)
                #pragma unroll
                for (int j = 0; j < 4; ++j)
                    acc[i][j] += a[i] * b[j];
        }
        __syncthreads();
    }

    #pragma unroll
    for (int j = 0; j < 4; ++j) {
        int col = col0 + tx * 4 + j;
        float bv = bias[col];
        #pragma unroll
        for (int i = 0; i < 4; ++i) {
            int row = row0 + ty * 4 + i;
            out[(size_t)row * 1024 + col] = acc[i][j] + bv;
        }
    }
}

__global__ __launch_bounds__(256) void sparse_attn_fb(
    const float* __restrict__ qf, const float* __restrict__ kf,
    const float* __restrict__ vf, const unsigned int* __restrict__ maskbits,
    float* __restrict__ attnf)
{
    __shared__ float kbuf[64][64];
    __shared__ float vbuf[64][64];
    __shared__ float sbuf[64][65];
    const int m  = blockIdx.x & 31;
    const int bh = blockIdx.x >> 5;
    const int b  = bh >> 4, h = bh & 15;
    const int t  = threadIdx.x;
    const int qr = t >> 2;
    const int dg = t & 3;
    const int d0 = dg * 16;

    float qreg[16];
    {
        const float* qp = qf + ((size_t)bh * NN + m * 64 + qr) * HD64 + d0;
        #pragma unroll
        for (int j = 0; j < 16; j += 4) {
            float4 v = *(const float4*)(qp + j);
            qreg[j] = v.x; qreg[j+1] = v.y; qreg[j+2] = v.z; qreg[j+3] = v.w;
        }
    }

    const unsigned int mask = maskbits[bh * 32 + m];
    float macc = -INFINITY, lacc = 0.f;
    float oacc[16];
    #pragma unroll
    for (int j = 0; j < 16; ++j) oacc[j] = 0.f;

    for (int nb = 0; nb < 32; ++nb) {
        if (!((mask >> nb) & 1u)) continue;
        __syncthreads();
        {
            const float* gk = kf + ((size_t)bh * NN + nb * 64) * HD64;
            const float* gv = vf + ((size_t)bh * NN + nb * 64) * HD64;
            #pragma unroll
            for (int i = 0; i < 4; ++i) {
                async_copy16(gk + t * 4 + i * 1024, (char*)kbuf + t * 16 + i * 4096);
                async_copy16(gv + t * 4 + i * 1024, (char*)vbuf + t * 16 + i * 4096);
            }
        }
        __syncthreads();

        float bmax = -INFINITY;
        for (int kk = 0; kk < 64; ++kk) {
            float s = 0.f;
            #pragma unroll
            for (int j = 0; j < 16; ++j) s += qreg[j] * kbuf[kk][d0 + j];
            s += __shfl_xor(s, 1);
            s += __shfl_xor(s, 2);
            s *= SCALE_F;
            if (dg == 0) sbuf[qr][kk] = s;
            bmax = fmaxf(bmax, s);
        }
        float mnew  = fmaxf(macc, bmax);
        float alpha = expf(macc - mnew);
        lacc *= alpha;
        #pragma unroll
        for (int j = 0; j < 16; ++j) oacc[j] *= alpha;
        for (int kk = 0; kk < 64; ++kk) {
            float p = expf(sbuf[qr][kk] - mnew);
            lacc += p;
            #pragma unroll
            for (int j = 0; j < 16; ++j) oacc[j] += p * vbuf[kk][d0 + j];
        }
        macc = mnew;
    }

    float inv = (lacc > 0.f) ? (1.f / lacc) : 0.f;
    size_t orow = ((size_t)(b * NN + m * 64 + qr)) * DIMD + h * 64 + d0;
    #pragma unroll
    for (int j = 0; j < 16; ++j) attnf[orow + j] = oacc[j] * inv;
}

// ---------------------------------------------------------------------------
extern "C" void kernel_launch(void* const* d_in, const int* in_sizes, int n_in,
                              void* d_out, int out_size, void* d_ws, size_t ws_size,
                              hipStream_t stream)
{
    const float* x      = (const float*)d_in[0];
    const float* qkv_w  = (const float*)d_in[1];
    const float* proj_w = (const float*)d_in[2];
    const float* proj_b = (const float*)d_in[3];
    float* out = (float*)d_out;

    // Carve (80,220,160 B, proven):
    //   C 16.8M: q  — fp32 [bh][n][64] from qkv, then in-place f16 hi|lo [bh][n][128]
    //   D 16.8M: k  — same
    //   E 16.8M: vf fp32
    //   qbf/kbf 512K | mask 4K
    //   A 16.8M: Axs (x-split; reused as attention output)
    //   B 12.6M: Wqs (qkv_w split; head reused for proj_w; tail 8.4M = vt)
    float* qC = (float*)d_ws;
    float* kD = qC + 4194304;
    float* vE = kD + 4194304;
    float* qbf = vE + 4194304;
    float* kbf = qbf + 65536;
    unsigned int* maskb = (unsigned int*)(kbf + 65536);
    short* Axs = (short*)(maskb + 1024);
    short* Wqs = Axs + (size_t)4096 * 2048;
    f16* vt = (f16*)((char*)Wqs + 4194304);
    const size_t need_fast = (size_t)((char*)(Wqs + (size_t)3072 * 2048) - (char*)d_ws);

    if (ws_size >= need_fast) {
        split_bf16_kernel<<<4096, 256, 0, stream>>>(x, Axs, 1048576);
        split_bf16_kernel<<<3072, 256, 0, stream>>>(qkv_w, Wqs, 786432);
        qkv_mfma_kernel<<<dim3(24, 32), 256, 0, stream>>>(Axs, Wqs, qC, kD, vE);
        block_mean_kernel<<<512, 256, 0, stream>>>(qC, kD, qbf, kbf);
        block_scores_kernel<<<32, 128, 0, stream>>>(qbf, kbf, maskb, 1.0f);
        split_qk_inplace_kernel<<<2048, 256, 0, stream>>>(qC, kD);
        split_bf16_kernel<<<1024, 256, 0, stream>>>(proj_w, Wqs, 262144);
        transpose_vt_kernel<<<1024, 256, 0, stream>>>(vE, vt);
        sparse_attn_mfma_kernel<<<1024, 256, 0, stream>>>((const f16*)qC, (const f16*)kD, vt, maskb, Axs);
        proj_mfma_kernel<<<dim3(16, 32), 256, 0, stream>>>(Axs, Wqs, proj_b, out);
    } else {
        float* qf2  = (float*)d_ws;
        float* kf2  = qf2 + 4194304;
        float* vf2  = kf2 + 4194304;
        float* qbf2 = vf2 + 4194304;
        float* kbf2 = qbf2 + 65536;
        unsigned int* maskb2 = (unsigned int*)(kbf2 + 65536);
        float* attnf = (float*)(maskb2 + 1024);
        qkv_gemm_fb<<<dim3(48, 64), 256, 0, stream>>>(x, qkv_w, qf2, kf2, vf2);
        block_mean_kernel<<<512, 256, 0, stream>>>(qf2, kf2, qbf2, kbf2);
        block_scores_kernel<<<32, 128, 0, stream>>>(qbf2, kbf2, maskb2, SCALE_F);
        sparse_attn_fb<<<1024, 256, 0, stream>>>(qf2, kf2, vf2, maskb2, attnf);
        proj_gemm_fb<<<dim3(16, 64), 256, 0, stream>>>(attnf, proj_w, proj_b, out);
    }
}

// Round 9
// 307.872 us; speedup vs baseline: 1.2359x; 1.2359x over previous
//
#include <hip/hip_runtime.h>
#include <hip/hip_bf16.h>

// Problem constants (B=2, N=2048, DIM=1024, H=16, HD=64, BS=64, M=32)
#define BB 2
#define NN 2048
#define DIMD 1024
#define HH 16
#define HD64 64
#define MB 32
#define SCALE_F 0.125f   // HD^-0.5

typedef __attribute__((ext_vector_type(8))) short bf16x8;
typedef __attribute__((ext_vector_type(4))) float f32x4;
typedef _Float16 f16;
typedef __attribute__((ext_vector_type(8))) _Float16 f16x8;

#define LSTR 72   // padded LDS row stride (f16): 144B rows, 16B-aligned

__device__ __forceinline__ unsigned short bf16_hi(float f) {
    return __builtin_bit_cast(unsigned short, __float2bfloat16(f));
}
__device__ __forceinline__ float bf16_val(unsigned short u) {
    return __bfloat162float(__builtin_bit_cast(__hip_bfloat16, u));
}
__device__ __forceinline__ void async_copy16(const void* g, void* l) {
    __builtin_amdgcn_global_load_lds((const __attribute__((address_space(1))) void*)g,
                                     (__attribute__((address_space(3))) void*)l, 16, 0, 0);
}

// ===========================================================================
// FAST PATH
// ===========================================================================

// Fused input split: blocks [0,4096) split x -> Axs; [4096,7168) split qkv_w -> Wqs.
// fp32 [rows][1024] -> bf16 hi|lo [rows][2048].
__global__ __launch_bounds__(256) void split_in_fused_kernel(
    const float* __restrict__ x, short* __restrict__ Axs,
    const float* __restrict__ w, short* __restrict__ Wqs)
{
    const int bid = blockIdx.x;
    const float* src; short* dst; int idx;
    if (bid < 4096) { src = x; dst = Axs; idx = bid * 256 + threadIdx.x; }
    else            { src = w; dst = Wqs; idx = (bid - 4096) * 256 + threadIdx.x; }
    int e = idx * 4;
    int r = e >> 10, c = e & 1023;
    float4 v = *(const float4*)(src + e);
    unsigned short h0 = bf16_hi(v.x), h1 = bf16_hi(v.y), h2 = bf16_hi(v.z), h3 = bf16_hi(v.w);
    unsigned short l0 = bf16_hi(v.x - bf16_val(h0));
    unsigned short l1 = bf16_hi(v.y - bf16_val(h1));
    unsigned short l2 = bf16_hi(v.z - bf16_val(h2));
    unsigned short l3 = bf16_hi(v.w - bf16_val(h3));
    size_t base = (size_t)r * 2048 + c;
    *(ushort4*)(dst + base)        = make_ushort4(h0, h1, h2, h3);
    *(ushort4*)(dst + base + 1024) = make_ushort4(l0, l1, l2, l3);
}

// QKV GEMM via bf16x3 MFMA. Round-6 staging lane order (4 consecutive lanes =
// one 64B global segment — coalescer is lane-order-sensitive, R8 lesson) PLUS
// an XOR k-chunk swizzle WITHIN each segment: lane l fetches k-chunk
// (l&3)^((l>>3)&3). Frag reads then hit uniform 2-way banks (free, m136).
__global__ __launch_bounds__(256) void qkv_mfma_kernel(
    const short* __restrict__ A, const short* __restrict__ W,
    float* __restrict__ qf, float* __restrict__ kf, float* __restrict__ vf)
{
    __shared__ short As[128 * 32];
    __shared__ short Bs[128 * 32];
    const int tid = threadIdx.x;
    const int lane = tid & 63;
    const int wave = tid >> 6;
    const int row0 = blockIdx.y * 128;
    const int col0 = blockIdx.x * 128;
    const int wm = wave & 1, wn = wave >> 1;

    f32x4 acc[4][4];
    const f32x4 zero = {0.f, 0.f, 0.f, 0.f};
    #pragma unroll
    for (int i = 0; i < 4; ++i)
        #pragma unroll
        for (int j = 0; j < 4; ++j) acc[i][j] = zero;

    const int ldr = lane >> 2;                              // row in 16-row chunk
    const int lko = (((lane & 3) ^ ((lane >> 3) & 3))) * 8; // swizzled k-chunk
    const int rsl = ((lane >> 4) ^ ((lane >> 1) & 3)) * 8;  // frag-read slot

    for (int kt = 0; kt < 96; ++kt) {
        const int seg = kt >> 5;
        const int kk = (kt & 31) << 5;
        const int ka0 = kk + (seg == 2 ? 1024 : 0);
        const int kw0 = kk + (seg == 1 ? 1024 : 0);
        #pragma unroll
        for (int i = 0; i < 2; ++i) {
            const int chunk = wave * 2 + i;          // 0..7 (16 rows each)
            const short* gA = A + (size_t)(row0 + chunk * 16 + ldr) * 2048 + ka0 + lko;
            const short* gB = W + (size_t)(col0 + chunk * 16 + ldr) * 2048 + kw0 + lko;
            async_copy16(gA, (char*)As + chunk * 1024);
            async_copy16(gB, (char*)Bs + chunk * 1024);
        }
        __syncthreads();
        bf16x8 af[4], bfr[4];
        #pragma unroll
        for (int mi = 0; mi < 4; ++mi)
            af[mi] = *(const bf16x8*)(As + (wm * 64 + mi * 16 + (lane & 15)) * 32 + rsl);
        #pragma unroll
        for (int ni = 0; ni < 4; ++ni)
            bfr[ni] = *(const bf16x8*)(Bs + (wn * 64 + ni * 16 + (lane & 15)) * 32 + rsl);
        #pragma unroll
        for (int mi = 0; mi < 4; ++mi)
            #pragma unroll
            for (int ni = 0; ni < 4; ++ni)
                acc[mi][ni] = __builtin_amdgcn_mfma_f32_16x16x32_bf16(af[mi], bfr[ni], acc[mi][ni], 0, 0, 0);
        __syncthreads();
    }

    // epilogue (round-6 proven): scatter fp32 into q/k/v [bh][n][64], q scaled
    #pragma unroll
    for (int ni = 0; ni < 4; ++ni) {
        int gc = col0 + wn * 64 + ni * 16 + (lane & 15);
        int tsel = gc >> 10;
        int h = (gc >> 6) & 15;
        int d = gc & 63;
        float* dst = (tsel == 0) ? qf : (tsel == 1) ? kf : vf;
        float sc = (tsel == 0) ? SCALE_F : 1.0f;
        #pragma unroll
        for (int mi = 0; mi < 4; ++mi) {
            int gr0 = row0 + wm * 64 + mi * 16 + (lane >> 4) * 4;
            #pragma unroll
            for (int r = 0; r < 4; ++r) {
                int gr = gr0 + r;
                int bb = gr >> 11, n = gr & 2047;
                dst[(((size_t)((bb << 4) + h)) * NN + n) * HD64 + d] = acc[mi][ni][r] * sc;
            }
        }
    }
}

// Fused prep: blocks [0,2048) in-place split q/k fp32->f16 hi|lo;
// [2048,3072) transpose v -> vt f16; [3072,4096) split proj_w -> Wqs head.
__global__ __launch_bounds__(256) void prep_fused_kernel(
    float* __restrict__ qbuf, float* __restrict__ kbuf,
    const float* __restrict__ vf, f16* __restrict__ vt,
    const float* __restrict__ projw, short* __restrict__ Wdst)
{
    __shared__ float smem[4160];
    const int bid = blockIdx.x;
    const int t = threadIdx.x;
    if (bid < 2048) {
        // in-place split: LDS-staged, barrier orders all reads before writes
        float* buf = (bid < 1024) ? qbuf : kbuf;
        const int row0 = (bid & 1023) * 64;
        const float* src = buf + (size_t)row0 * 64;
        #pragma unroll
        for (int i = 0; i < 4; ++i)
            *(float4*)(smem + t * 4 + i * 1024) = *(const float4*)(src + t * 4 + i * 1024);
        __syncthreads();
        const int r = t >> 2, d0 = (t & 3) * 16;
        f16x8 hv0, hv1, lv0, lv1;
        #pragma unroll
        for (int j = 0; j < 8; ++j) {
            float v = smem[r * 64 + d0 + j];
            f16 hh = (f16)v;
            hv0[j] = hh; lv0[j] = (f16)(v - (float)hh);
        }
        #pragma unroll
        for (int j = 0; j < 8; ++j) {
            float v = smem[r * 64 + d0 + 8 + j];
            f16 hh = (f16)v;
            hv1[j] = hh; lv1[j] = (f16)(v - (float)hh);
        }
        f16* dst = (f16*)buf + ((size_t)(row0 + r)) * 128;
        *(f16x8*)(dst + d0)          = hv0;
        *(f16x8*)(dst + d0 + 8)      = hv1;
        *(f16x8*)(dst + 64 + d0)     = lv0;
        *(f16x8*)(dst + 64 + d0 + 8) = lv1;
    } else if (bid < 3072) {
        // transpose v: vf fp32 [bh][n][64] -> vt f16 [bh][d][2048]
        const int b2 = bid - 2048;
        const int nb = b2 & 31, bh = b2 >> 5;
        float (*tile)[65] = (float(*)[65])smem;
        {
            const int r = t >> 2, c0 = (t & 3) * 16;
            const float* src = vf + ((size_t)bh * NN + nb * 64 + r) * HD64 + c0;
            #pragma unroll
            for (int j = 0; j < 16; j += 4) {
                float4 v4 = *(const float4*)(src + j);
                tile[r][c0 + j]     = v4.x;
                tile[r][c0 + j + 1] = v4.y;
                tile[r][c0 + j + 2] = v4.z;
                tile[r][c0 + j + 3] = v4.w;
            }
        }
        __syncthreads();
        {
            const int d = t >> 2, n0 = (t & 3) * 16;
            f16x8 o0, o1;
            #pragma unroll
            for (int j = 0; j < 8; ++j) o0[j] = (f16)tile[n0 + j][d];
            #pragma unroll
            for (int j = 0; j < 8; ++j) o1[j] = (f16)tile[n0 + 8 + j][d];
            f16* dst = vt + ((size_t)bh * HD64 + d) * NN + nb * 64 + n0;
            *(f16x8*)(dst)     = o0;
            *(f16x8*)(dst + 8) = o1;
        }
    } else {
        // split proj_w fp32 [1024][1024] -> bf16 hi|lo [1024][2048]
        int idx = (bid - 3072) * 256 + t;
        int e = idx * 4;
        int r = e >> 10, c = e & 1023;
        float4 v = *(const float4*)(projw + e);
        unsigned short h0 = bf16_hi(v.x), h1 = bf16_hi(v.y), h2 = bf16_hi(v.z), h3 = bf16_hi(v.w);
        unsigned short l0 = bf16_hi(v.x - bf16_val(h0));
        unsigned short l1 = bf16_hi(v.y - bf16_val(h1));
        unsigned short l2 = bf16_hi(v.z - bf16_val(h2));
        unsigned short l3 = bf16_hi(v.w - bf16_val(h3));
        size_t base = (size_t)r * 2048 + c;
        *(ushort4*)(Wdst + base)        = make_ushort4(h0, h1, h2, h3);
        *(ushort4*)(Wdst + base + 1024) = make_ushort4(l0, l1, l2, l3);
    }
}

// Proj GEMM via bf16x3 MFMA + bias. Round-6 shape (128x64, 4 waves of 32x64),
// round-6 staging order + XOR swizzle (same as qkv).
__global__ __launch_bounds__(256) void proj_mfma_kernel(
    const short* __restrict__ A, const short* __restrict__ W,
    const float* __restrict__ bias, float* __restrict__ out)
{
    __shared__ short As[128 * 32];
    __shared__ short Bs[64 * 32];
    const int tid = threadIdx.x;
    const int lane = tid & 63;
    const int wave = tid >> 6;
    const int row0 = blockIdx.y * 128;
    const int col0 = blockIdx.x * 64;

    f32x4 acc[2][4];
    const f32x4 zero = {0.f, 0.f, 0.f, 0.f};
    #pragma unroll
    for (int i = 0; i < 2; ++i)
        #pragma unroll
        for (int j = 0; j < 4; ++j) acc[i][j] = zero;

    const int ldr = lane >> 2;
    const int lko = (((lane & 3) ^ ((lane >> 3) & 3))) * 8;
    const int rsl = ((lane >> 4) ^ ((lane >> 1) & 3)) * 8;

    for (int kt = 0; kt < 96; ++kt) {
        const int seg = kt >> 5;
        const int kk = (kt & 31) << 5;
        const int ka0 = kk + (seg == 2 ? 1024 : 0);
        const int kw0 = kk + (seg == 1 ? 1024 : 0);
        #pragma unroll
        for (int i = 0; i < 2; ++i) {
            const int chunk = wave * 2 + i;
            const short* gA = A + (size_t)(row0 + chunk * 16 + ldr) * 2048 + ka0 + lko;
            async_copy16(gA, (char*)As + chunk * 1024);
        }
        {
            const short* gB = W + (size_t)(col0 + wave * 16 + ldr) * 2048 + kw0 + lko;
            async_copy16(gB, (char*)Bs + wave * 1024);
        }
        __syncthreads();
        bf16x8 af[2], bfr[4];
        #pragma unroll
        for (int mi = 0; mi < 2; ++mi)
            af[mi] = *(const bf16x8*)(As + (wave * 32 + mi * 16 + (lane & 15)) * 32 + rsl);
        #pragma unroll
        for (int ni = 0; ni < 4; ++ni)
            bfr[ni] = *(const bf16x8*)(Bs + (ni * 16 + (lane & 15)) * 32 + rsl);
        #pragma unroll
        for (int mi = 0; mi < 2; ++mi)
            #pragma unroll
            for (int ni = 0; ni < 4; ++ni)
                acc[mi][ni] = __builtin_amdgcn_mfma_f32_16x16x32_bf16(af[mi], bfr[ni], acc[mi][ni], 0, 0, 0);
        __syncthreads();
    }

    #pragma unroll
    for (int ni = 0; ni < 4; ++ni) {
        int gc = col0 + ni * 16 + (lane & 15);
        float bv = bias[gc];
        #pragma unroll
        for (int mi = 0; mi < 2; ++mi) {
            int gr0 = row0 + wave * 32 + mi * 16 + (lane >> 4) * 4;
            #pragma unroll
            for (int r = 0; r < 4; ++r)
                out[(size_t)(gr0 + r) * 1024 + gc] = acc[mi][ni][r] + bv;
        }
    }
}

// ---------------------------------------------------------------------------
// Sparse block attention on MFMA (proven). 256 thr = 4 waves/(bh,m).
// Inputs pre-split: qs/ks f16 hi|lo [bh][n][128] (q pre-scaled), vt f16 [bh][d][n].
// ---------------------------------------------------------------------------
__global__ __launch_bounds__(256) void sparse_attn_mfma_kernel(
    const f16* __restrict__ qs, const f16* __restrict__ ks,
    const f16* __restrict__ vt, const unsigned int* __restrict__ maskbits,
    short* __restrict__ aout)
{
    __shared__ f16 Qh[64 * LSTR], Ql[64 * LSTR];
    __shared__ f16 Kh[64 * LSTR], Kl[64 * LSTR];
    __shared__ f16 Vt[64 * LSTR];
    __shared__ f16 Pb[64 * LSTR];

    const int m  = blockIdx.x & 31;
    const int bh = blockIdx.x >> 5;
    const int b  = bh >> 4, h = bh & 15;
    const int tid = threadIdx.x;
    const int lane = tid & 63;
    const int wave = tid >> 6;
    const f32x4 zero = {0.f, 0.f, 0.f, 0.f};

    {
        const int r = tid >> 2, c0 = (tid & 3) * 16;
        const f16* src = qs + ((size_t)bh * NN + m * 64 + r) * 128 + c0;
        *(f16x8*)(Qh + r * LSTR + c0)     = *(const f16x8*)(src);
        *(f16x8*)(Qh + r * LSTR + c0 + 8) = *(const f16x8*)(src + 8);
        *(f16x8*)(Ql + r * LSTR + c0)     = *(const f16x8*)(src + 64);
        *(f16x8*)(Ql + r * LSTR + c0 + 8) = *(const f16x8*)(src + 72);
    }
    __syncthreads();

    const unsigned int mask = maskbits[bh * 32 + m];
    f32x4 s_acc[4], o_acc[4];
    float macc[4], lacc[4];
    #pragma unroll
    for (int r = 0; r < 4; ++r) { macc[r] = -INFINITY; lacc[r] = 0.f; }
    #pragma unroll
    for (int t = 0; t < 4; ++t) o_acc[t] = zero;

    const int arow = wave * 16 + (lane & 15);
    const int kofs = (lane >> 4) * 8;

    for (int nb = 0; nb < 32; ++nb) {
        if (!((mask >> nb) & 1u)) continue;
        __syncthreads();

        {
            const int r = tid >> 2, c0 = (tid & 3) * 16;
            const f16* srck = ks + ((size_t)bh * NN + nb * 64 + r) * 128 + c0;
            *(f16x8*)(Kh + r * LSTR + c0)     = *(const f16x8*)(srck);
            *(f16x8*)(Kh + r * LSTR + c0 + 8) = *(const f16x8*)(srck + 8);
            *(f16x8*)(Kl + r * LSTR + c0)     = *(const f16x8*)(srck + 64);
            *(f16x8*)(Kl + r * LSTR + c0 + 8) = *(const f16x8*)(srck + 72);
            const f16* srcv = vt + ((size_t)bh * HD64 + r) * NN + nb * 64 + c0;
            *(f16x8*)(Vt + r * LSTR + c0)     = *(const f16x8*)(srcv);
            *(f16x8*)(Vt + r * LSTR + c0 + 8) = *(const f16x8*)(srcv + 8);
        }
        __syncthreads();

        #pragma unroll
        for (int t = 0; t < 4; ++t) s_acc[t] = zero;
        #pragma unroll
        for (int c = 0; c < 2; ++c) {
            f16x8 ah = *(const f16x8*)(Qh + arow * LSTR + c * 32 + kofs);
            f16x8 al = *(const f16x8*)(Ql + arow * LSTR + c * 32 + kofs);
            #pragma unroll
            for (int t = 0; t < 4; ++t) {
                f16x8 bh_ = *(const f16x8*)(Kh + (t * 16 + (lane & 15)) * LSTR + c * 32 + kofs);
                f16x8 bl_ = *(const f16x8*)(Kl + (t * 16 + (lane & 15)) * LSTR + c * 32 + kofs);
                s_acc[t] = __builtin_amdgcn_mfma_f32_16x16x32_f16(ah, bh_, s_acc[t], 0, 0, 0);
                s_acc[t] = __builtin_amdgcn_mfma_f32_16x16x32_f16(ah, bl_, s_acc[t], 0, 0, 0);
                s_acc[t] = __builtin_amdgcn_mfma_f32_16x16x32_f16(al, bh_, s_acc[t], 0, 0, 0);
            }
        }

        float alpha[4], psum[4];
        #pragma unroll
        for (int r = 0; r < 4; ++r) {
            float v0 = fmaxf(fmaxf(s_acc[0][r], s_acc[1][r]), fmaxf(s_acc[2][r], s_acc[3][r]));
            #pragma unroll
            for (int off = 1; off < 16; off <<= 1)
                v0 = fmaxf(v0, __shfl_xor(v0, off));
            float mnew = fmaxf(macc[r], v0);
            alpha[r] = expf(macc[r] - mnew);
            macc[r] = mnew;
            psum[r] = 0.f;
        }
        #pragma unroll
        for (int t = 0; t < 4; ++t) {
            #pragma unroll
            for (int r = 0; r < 4; ++r) {
                float p = expf(s_acc[t][r] - macc[r]);
                psum[r] += p;
                Pb[(wave * 16 + (lane >> 4) * 4 + r) * LSTR + t * 16 + (lane & 15)] = (f16)p;
            }
        }
        #pragma unroll
        for (int r = 0; r < 4; ++r) {
            float v0 = psum[r];
            #pragma unroll
            for (int off = 1; off < 16; off <<= 1) v0 += __shfl_xor(v0, off);
            lacc[r] = lacc[r] * alpha[r] + v0;
            #pragma unroll
            for (int t = 0; t < 4; ++t) o_acc[t][r] *= alpha[r];
        }
        __syncthreads();

        #pragma unroll
        for (int c = 0; c < 2; ++c) {
            f16x8 af = *(const f16x8*)(Pb + arow * LSTR + c * 32 + kofs);
            #pragma unroll
            for (int t = 0; t < 4; ++t) {
                f16x8 bf = *(const f16x8*)(Vt + (t * 16 + (lane & 15)) * LSTR + c * 32 + kofs);
                o_acc[t] = __builtin_amdgcn_mfma_f32_16x16x32_f16(af, bf, o_acc[t], 0, 0, 0);
            }
        }
    }

    float inv[4];
    #pragma unroll
    for (int r = 0; r < 4; ++r) inv[r] = (lacc[r] > 0.f) ? (1.f / lacc[r]) : 0.f;
    #pragma unroll
    for (int t = 0; t < 4; ++t) {
        int gc = h * 64 + t * 16 + (lane & 15);
        #pragma unroll
        for (int r = 0; r < 4; ++r) {
            int grow = b * NN + m * 64 + wave * 16 + (lane >> 4) * 4 + r;
            float v = o_acc[t][r] * inv[r];
            unsigned short hh = bf16_hi(v);
            unsigned short ll = bf16_hi(v - bf16_val(hh));
            aout[(size_t)grow * 2048 + gc] = (short)hh;
            aout[(size_t)grow * 2048 + 1024 + gc] = (short)ll;
        }
    }
}

// ===========================================================================
// SHARED / FALLBACK KERNELS
// ===========================================================================

__global__ __launch_bounds__(256) void block_mean_kernel(
    const float* __restrict__ qf, const float* __restrict__ kf,
    float* __restrict__ qbf, float* __restrict__ kbf)
{
    int idx = blockIdx.x * 256 + threadIdx.x;
    const float* src = (idx < 65536) ? qf : kf;
    float* dst       = (idx < 65536) ? qbf : kbf;
    int e = idx & 65535;
    int d = e & 63;
    int r = e >> 6;
    size_t base = (size_t)r * 4096 + d;
    float s = 0.f;
    #pragma unroll
    for (int i = 0; i < 64; ++i) s += src[base + (size_t)i * 64];
    dst[e] = s * (1.f / 64.f);
}

__global__ __launch_bounds__(128) void block_scores_kernel(
    const float* __restrict__ qbf, const float* __restrict__ kbf,
    unsigned int* __restrict__ maskbits, float scale)
{
    __shared__ float qs_[32][64];
    __shared__ float ks_[32][64];
    __shared__ float cb[32][32];
    const int bh = blockIdx.x;
    const int tid = threadIdx.x;

    #pragma unroll
    for (int i = 0; i < 16; ++i) {
        int e = tid + i * 128;
        qs_[e >> 6][e & 63] = qbf[(size_t)bh * 2048 + e];
        ks_[e >> 6][e & 63] = kbf[(size_t)bh * 2048 + e];
    }
    __syncthreads();

    #pragma unroll
    for (int i = 0; i < 8; ++i) {
        int idx = tid + i * 128;
        int r = idx >> 5, c = idx & 31;
        float s = 0.f;
        #pragma unroll
        for (int d = 0; d < 64; ++d) s += qs_[r][d] * ks_[c][d];
        cb[r][c] = s * scale;
    }
    __syncthreads();

    if (tid < 32) {
        float m1 = -INFINITY, m2 = -INFINITY;
        for (int n = 0; n < 32; ++n) {
            float v = cb[tid][n];
            if (v > m1) { m2 = m1; m1 = v; }
            else if (v > m2) { m2 = v; }
        }
        unsigned int bits = 1u << tid;
        for (int n = 0; n < 32; ++n)
            if (cb[tid][n] >= m2) bits |= 1u << n;
        maskbits[bh * 32 + tid] = bits;
    }
}

__global__ __launch_bounds__(256) void qkv_gemm_fb(
    const float* __restrict__ x, const float* __restrict__ w,
    float* __restrict__ qf, float* __restrict__ kf, float* __restrict__ vf)
{
    __shared__ float As[64][33];
    __shared__ float Bs[64][33];
    const int tid = threadIdx.x;
    const int row0 = blockIdx.y * 64;
    const int col0 = blockIdx.x * 64;
    const int ty = tid >> 4, tx = tid & 15;

    float acc[4][4] = {};
    for (int k0 = 0; k0 < 1024; k0 += 32) {
        #pragma unroll
        for (int i = 0; i < 8; ++i) {
            int e = tid + i * 256;
            int r = e >> 5, c = e & 31;
            As[r][c] = x[(size_t)(row0 + r) * 1024 + k0 + c];
            Bs[r][c] = w[(size_t)(col0 + r) * 1024 + k0 + c];
        }
        __syncthreads();
        #pragma unroll
        for (int kk = 0; kk < 32; ++kk) {
            float a[4], b[4];
            #pragma unroll
            for (int i = 0; i < 4; ++i) a[i] = As[ty * 4 + i][kk];
            #pragma unroll
            for (int j = 0; j < 4; ++j) b[j] = Bs[tx * 4 + j][kk];
            #pragma unroll
            for (int i = 0; i < 4; ++i)
                #pragma unroll
                for (int j = 0; j < 4; ++j)
                    acc[i][j] += a[i] * b[j];
        }
        __syncthreads();
    }

    const int tsel = col0 >> 10;
    const int h    = (col0 & 1023) >> 6;
    float* dstbuf = (tsel == 0) ? qf : (tsel == 1) ? kf : vf;
    #pragma unroll
    for (int i = 0; i < 4; ++i) {
        int row = row0 + ty * 4 + i;
        int b   = row >> 11, n = row & 2047;
        size_t rb = ((size_t)(b * HH + h) * NN + n) * HD64;
        #pragma unroll
        for (int j = 0; j < 4; ++j)
            dstbuf[rb + tx * 4 + j] = acc[i][j];
    }
}

__global__ __launch_bounds__(256) void proj_gemm_fb(
    const float* __restrict__ attn, const float* __restrict__ w,
    const float* __restrict__ bias, float* __restrict__ out)
{
    __shared__ float As[64][33];
    __shared__ float Bs[64][33];
    const int tid = threadIdx.x;
    const int row0 = blockIdx.y * 64;
    const int col0 = blockIdx.x * 64;
    const int ty = tid >> 4, tx = tid & 15;

    float acc[4][4] = {};
    for (int k0 = 0; k0 < 1024; k0 += 32) {
        #pragma unroll
        for (int i = 0; i < 8; ++i) {
            int e = tid + i * 256;
            int r = e >> 5, c = e & 31;
            As[r][c] = attn[(size_t)(row0 + r) * 1024 + k0 + c];
            Bs[r][c] = w[(size_t)(col0 + r) * 1024 + k0 + c];
        }
        __syncthreads();
        #pragma unroll
        for (int kk = 0; kk < 32; ++kk) {
            float a[4], b[4];
            #pragma unroll
            for (int i = 0; i < 4; ++i) a[i] = As[ty * 4 + i][kk];
            #pragma unroll
            for (int j = 0; j < 4; ++j) b[j] = Bs[tx * 4 + j][kk];
            #pragma unroll
            for (int i = 0; i < 4; ++i)
                #pragma unroll
                for (int j = 0; j < 4; ++j)
                    acc[i][j] += a[i] * b[j];
        }
        __syncthreads();
    }

    #pragma unroll
    for (int j = 0; j < 4; ++j) {
        int col = col0 + tx * 4 + j;
        float bv = bias[col];
        #pragma unroll
        for (int i = 0; i < 4; ++i) {
            int row = row0 + ty * 4 + i;
            out[(size_t)row * 1024 + col] = acc[i][j] + bv;
        }
    }
}

__global__ __launch_bounds__(256) void sparse_attn_fb(
    const float* __restrict__ qf, const float* __restrict__ kf,
    const float* __restrict__ vf, const unsigned int* __restrict__ maskbits,
    float* __restrict__ attnf)
{
    __shared__ float kbuf[64][64];
    __shared__ float vbuf[64][64];
    __shared__ float sbuf[64][65];
    const int m  = blockIdx.x & 31;
    const int bh = blockIdx.x >> 5;
    const int b  = bh >> 4, h = bh & 15;
    const int t  = threadIdx.x;
    const int qr = t >> 2;
    const int dg = t & 3;
    const int d0 = dg * 16;

    float qreg[16];
    {
        const float* qp = qf + ((size_t)bh * NN + m * 64 + qr) * HD64 + d0;
        #pragma unroll
        for (int j = 0; j < 16; j += 4) {
            float4 v = *(const float4*)(qp + j);
            qreg[j] = v.x; qreg[j+1] = v.y; qreg[j+2] = v.z; qreg[j+3] = v.w;
        }
    }

    const unsigned int mask = maskbits[bh * 32 + m];
    float macc = -INFINITY, lacc = 0.f;
    float oacc[16];
    #pragma unroll
    for (int j = 0; j < 16; ++j) oacc[j] = 0.f;

    for (int nb = 0; nb < 32; ++nb) {
        if (!((mask >> nb) & 1u)) continue;
        __syncthreads();
        {
            const float* gk = kf + ((size_t)bh * NN + nb * 64) * HD64;
            const float* gv = vf + ((size_t)bh * NN + nb * 64) * HD64;
            #pragma unroll
            for (int i = 0; i < 4; ++i) {
                async_copy16(gk + t * 4 + i * 1024, (char*)kbuf + t * 16 + i * 4096);
                async_copy16(gv + t * 4 + i * 1024, (char*)vbuf + t * 16 + i * 4096);
            }
        }
        __syncthreads();

        float bmax = -INFINITY;
        for (int kk = 0; kk < 64; ++kk) {
            float s = 0.f;
            #pragma unroll
            for (int j = 0; j < 16; ++j) s += qreg[j] * kbuf[kk][d0 + j];
            s += __shfl_xor(s, 1);
            s += __shfl_xor(s, 2);
            s *= SCALE_F;
            if (dg == 0) sbuf[qr][kk] = s;
            bmax = fmaxf(bmax, s);
        }
        float mnew  = fmaxf(macc, bmax);
        float alpha = expf(macc - mnew);
        lacc *= alpha;
        #pragma unroll
        for (int j = 0; j < 16; ++j) oacc[j] *= alpha;
        for (int kk = 0; kk < 64; ++kk) {
            float p = expf(sbuf[qr][kk] - mnew);
            lacc += p;
            #pragma unroll
            for (int j = 0; j < 16; ++j) oacc[j] += p * vbuf[kk][d0 + j];
        }
        macc = mnew;
    }

    float inv = (lacc > 0.f) ? (1.f / lacc) : 0.f;
    size_t orow = ((size_t)(b * NN + m * 64 + qr)) * DIMD + h * 64 + d0;
    #pragma unroll
    for (int j = 0; j < 16; ++j) attnf[orow + j] = oacc[j] * inv;
}

// ---------------------------------------------------------------------------
extern "C" void kernel_launch(void* const* d_in, const int* in_sizes, int n_in,
                              void* d_out, int out_size, void* d_ws, size_t ws_size,
                              hipStream_t stream)
{
    const float* x      = (const float*)d_in[0];
    const float* qkv_w  = (const float*)d_in[1];
    const float* proj_w = (const float*)d_in[2];
    const float* proj_b = (const float*)d_in[3];
    float* out = (float*)d_out;

    // Carve (80,220,160 B, proven):
    //   C 16.8M: q — fp32 [bh][n][64] from qkv, then in-place f16 hi|lo [bh][n][128]
    //   D 16.8M: k — same | E 16.8M: vf fp32 | qbf/kbf 512K | mask 4K
    //   A 16.8M: Axs (x-split; reused as attention output)
    //   B 12.6M: Wqs (qkv_w split; head 4.2M reused for proj_w; tail 8.4M = vt)
    float* qC = (float*)d_ws;
    float* kD = qC + 4194304;
    float* vE = kD + 4194304;
    float* qbf = vE + 4194304;
    float* kbf = qbf + 65536;
    unsigned int* maskb = (unsigned int*)(kbf + 65536);
    short* Axs = (short*)(maskb + 1024);
    short* Wqs = Axs + (size_t)4096 * 2048;
    f16* vt = (f16*)((char*)Wqs + 4194304);
    const size_t need_fast = (size_t)((char*)(Wqs + (size_t)3072 * 2048) - (char*)d_ws);

    if (ws_size >= need_fast) {
        split_in_fused_kernel<<<7168, 256, 0, stream>>>(x, Axs, qkv_w, Wqs);
        qkv_mfma_kernel<<<dim3(24, 32), 256, 0, stream>>>(Axs, Wqs, qC, kD, vE);
        block_mean_kernel<<<512, 256, 0, stream>>>(qC, kD, qbf, kbf);
        block_scores_kernel<<<32, 128, 0, stream>>>(qbf, kbf, maskb, 1.0f);
        prep_fused_kernel<<<4096, 256, 0, stream>>>(qC, kD, vE, vt, proj_w, Wqs);
        sparse_attn_mfma_kernel<<<1024, 256, 0, stream>>>((const f16*)qC, (const f16*)kD, vt, maskb, Axs);
        proj_mfma_kernel<<<dim3(16, 32), 256, 0, stream>>>(Axs, Wqs, proj_b, out);
    } else {
        float* qf2  = (float*)d_ws;
        float* kf2  = qf2 + 4194304;
        float* vf2  = kf2 + 4194304;
        float* qbf2 = vf2 + 4194304;
        float* kbf2 = qbf2 + 65536;
        unsigned int* maskb2 = (unsigned int*)(kbf2 + 65536);
        float* attnf = (float*)(maskb2 + 1024);
        qkv_gemm_fb<<<dim3(48, 64), 256, 0, stream>>>(x, qkv_w, qf2, kf2, vf2);
        block_mean_kernel<<<512, 256, 0, stream>>>(qf2, kf2, qbf2, kbf2);
        block_scores_kernel<<<32, 128, 0, stream>>>(qbf2, kbf2, maskb2, SCALE_F);
        sparse_attn_fb<<<1024, 256, 0, stream>>>(qf2, kf2, vf2, maskb2, attnf);
        proj_gemm_fb<<<dim3(16, 64), 256, 0, stream>>>(attnf, proj_w, proj_b, out);
    }
}

// Round 10
// 286.184 us; speedup vs baseline: 1.3295x; 1.0758x over previous
//
#include <hip/hip_runtime.h>
#include <hip/hip_bf16.h>

// Problem constants (B=2, N=2048, DIM=1024, H=16, HD=64, BS=64, M=32)
#define BB 2
#define NN 2048
#define DIMD 1024
#define HH 16
#define HD64 64
#define MB 32
#define SCALE_F 0.125f   // HD^-0.5

typedef __attribute__((ext_vector_type(8))) short bf16x8;
typedef __attribute__((ext_vector_type(4))) float f32x4;
typedef _Float16 f16;
typedef __attribute__((ext_vector_type(8))) _Float16 f16x8;

#define LSTR 72   // padded LDS row stride (f16): 144B rows, 16B-aligned

__device__ __forceinline__ unsigned short bf16_hi(float f) {
    return __builtin_bit_cast(unsigned short, __float2bfloat16(f));
}
__device__ __forceinline__ float bf16_val(unsigned short u) {
    return __bfloat162float(__builtin_bit_cast(__hip_bfloat16, u));
}
__device__ __forceinline__ void async_copy16(const void* g, void* l) {
    __builtin_amdgcn_global_load_lds((const __attribute__((address_space(1))) void*)g,
                                     (__attribute__((address_space(3))) void*)l, 16, 0, 0);
}

// ===========================================================================
// FAST PATH
// ===========================================================================

// Fused input split: blocks [0,4096) split x -> Axs; [4096,7168) split qkv_w -> Wqs.
__global__ __launch_bounds__(256) void split_in_fused_kernel(
    const float* __restrict__ x, short* __restrict__ Axs,
    const float* __restrict__ w, short* __restrict__ Wqs)
{
    const int bid = blockIdx.x;
    const float* src; short* dst; int idx;
    if (bid < 4096) { src = x; dst = Axs; idx = bid * 256 + threadIdx.x; }
    else            { src = w; dst = Wqs; idx = (bid - 4096) * 256 + threadIdx.x; }
    int e = idx * 4;
    int r = e >> 10, c = e & 1023;
    float4 v = *(const float4*)(src + e);
    unsigned short h0 = bf16_hi(v.x), h1 = bf16_hi(v.y), h2 = bf16_hi(v.z), h3 = bf16_hi(v.w);
    unsigned short l0 = bf16_hi(v.x - bf16_val(h0));
    unsigned short l1 = bf16_hi(v.y - bf16_val(h1));
    unsigned short l2 = bf16_hi(v.z - bf16_val(h2));
    unsigned short l3 = bf16_hi(v.w - bf16_val(h3));
    size_t base = (size_t)r * 2048 + c;
    *(ushort4*)(dst + base)        = make_ushort4(h0, h1, h2, h3);
    *(ushort4*)(dst + base + 1024) = make_ushort4(l0, l1, l2, l3);
}

// QKV GEMM via bf16x3 MFMA. R9-proven staging (lane-order-preserving XOR
// k-chunk swizzle -> 0 bank conflicts, coalescing intact). Epilogue: fp32
// q/k/v scatter (q pre-scaled) + FUSED block-mean for q/k: each (bh,m,d) is
// owned by exactly one wave; sum acc over mi,r then quad-reduce via shfl.
__global__ __launch_bounds__(256) void qkv_mfma_kernel(
    const short* __restrict__ A, const short* __restrict__ W,
    float* __restrict__ qf, float* __restrict__ kf, float* __restrict__ vf,
    float* __restrict__ qbf, float* __restrict__ kbf)
{
    __shared__ short As[128 * 32];
    __shared__ short Bs[128 * 32];
    const int tid = threadIdx.x;
    const int lane = tid & 63;
    const int wave = tid >> 6;
    const int row0 = blockIdx.y * 128;
    const int col0 = blockIdx.x * 128;
    const int wm = wave & 1, wn = wave >> 1;

    f32x4 acc[4][4];
    const f32x4 zero = {0.f, 0.f, 0.f, 0.f};
    #pragma unroll
    for (int i = 0; i < 4; ++i)
        #pragma unroll
        for (int j = 0; j < 4; ++j) acc[i][j] = zero;

    const int ldr = lane >> 2;                              // row in 16-row chunk
    const int lko = (((lane & 3) ^ ((lane >> 3) & 3))) * 8; // swizzled k-chunk
    const int rsl = ((lane >> 4) ^ ((lane >> 1) & 3)) * 8;  // frag-read slot

    for (int kt = 0; kt < 96; ++kt) {
        const int seg = kt >> 5;
        const int kk = (kt & 31) << 5;
        const int ka0 = kk + (seg == 2 ? 1024 : 0);
        const int kw0 = kk + (seg == 1 ? 1024 : 0);
        #pragma unroll
        for (int i = 0; i < 2; ++i) {
            const int chunk = wave * 2 + i;
            const short* gA = A + (size_t)(row0 + chunk * 16 + ldr) * 2048 + ka0 + lko;
            const short* gB = W + (size_t)(col0 + chunk * 16 + ldr) * 2048 + kw0 + lko;
            async_copy16(gA, (char*)As + chunk * 1024);
            async_copy16(gB, (char*)Bs + chunk * 1024);
        }
        __syncthreads();
        bf16x8 af[4], bfr[4];
        #pragma unroll
        for (int mi = 0; mi < 4; ++mi)
            af[mi] = *(const bf16x8*)(As + (wm * 64 + mi * 16 + (lane & 15)) * 32 + rsl);
        #pragma unroll
        for (int ni = 0; ni < 4; ++ni)
            bfr[ni] = *(const bf16x8*)(Bs + (wn * 64 + ni * 16 + (lane & 15)) * 32 + rsl);
        #pragma unroll
        for (int mi = 0; mi < 4; ++mi)
            #pragma unroll
            for (int ni = 0; ni < 4; ++ni)
                acc[mi][ni] = __builtin_amdgcn_mfma_f32_16x16x32_bf16(af[mi], bfr[ni], acc[mi][ni], 0, 0, 0);
        __syncthreads();
    }

    // epilogue: scatter + fused block-mean
    const int gr_first = row0 + wm * 64;          // wave's 64-row token block
    const int bb = gr_first >> 11;
    const int mblk = (gr_first & 2047) >> 6;
    #pragma unroll
    for (int ni = 0; ni < 4; ++ni) {
        int gc = col0 + wn * 64 + ni * 16 + (lane & 15);
        int tsel = gc >> 10;
        int h = (gc >> 6) & 15;
        int d = gc & 63;
        float* dst = (tsel == 0) ? qf : (tsel == 1) ? kf : vf;
        float sc = (tsel == 0) ? SCALE_F : 1.0f;
        float colsum = 0.f;
        #pragma unroll
        for (int mi = 0; mi < 4; ++mi) {
            int gr0 = row0 + wm * 64 + mi * 16 + (lane >> 4) * 4;
            #pragma unroll
            for (int r = 0; r < 4; ++r) {
                int gr = gr0 + r;
                int n = gr & 2047;
                float v = acc[mi][ni][r] * sc;
                dst[(((size_t)((bb << 4) + h)) * NN + n) * HD64 + d] = v;
                colsum += v;
            }
        }
        if (tsel != 2) {
            colsum += __shfl_xor(colsum, 16);
            colsum += __shfl_xor(colsum, 32);
            if ((lane >> 4) == 0) {
                float* mdst = (tsel == 0) ? qbf : kbf;
                mdst[((size_t)((bb << 4) + h) * 32 + mblk) * 64 + d] = colsum * (1.f / 64.f);
            }
        }
    }
}

// Fused: blocks [0,32) block-scores + top-2 mask; blocks [32,1056) split
// proj_w fp32 [1024][1024] -> bf16 hi|lo into Wqs head (dead after qkv).
__global__ __launch_bounds__(256) void scores_splitw_kernel(
    const float* __restrict__ qbf, const float* __restrict__ kbf,
    unsigned int* __restrict__ maskbits, float scale,
    const float* __restrict__ projw, short* __restrict__ Wdst)
{
    __shared__ float qs_[32][64];
    __shared__ float ks_[32][64];
    __shared__ float cb[32][32];
    const int bid = blockIdx.x;
    const int tid = threadIdx.x;

    if (bid >= 32) {
        int idx = (bid - 32) * 256 + tid;
        int e = idx * 4;
        int r = e >> 10, c = e & 1023;
        float4 v = *(const float4*)(projw + e);
        unsigned short h0 = bf16_hi(v.x), h1 = bf16_hi(v.y), h2 = bf16_hi(v.z), h3 = bf16_hi(v.w);
        unsigned short l0 = bf16_hi(v.x - bf16_val(h0));
        unsigned short l1 = bf16_hi(v.y - bf16_val(h1));
        unsigned short l2 = bf16_hi(v.z - bf16_val(h2));
        unsigned short l3 = bf16_hi(v.w - bf16_val(h3));
        size_t base = (size_t)r * 2048 + c;
        *(ushort4*)(Wdst + base)        = make_ushort4(h0, h1, h2, h3);
        *(ushort4*)(Wdst + base + 1024) = make_ushort4(l0, l1, l2, l3);
        return;
    }

    #pragma unroll
    for (int i = 0; i < 8; ++i) {
        int e = tid + i * 256;
        qs_[e >> 6][e & 63] = qbf[(size_t)bid * 2048 + e];
        ks_[e >> 6][e & 63] = kbf[(size_t)bid * 2048 + e];
    }
    __syncthreads();

    #pragma unroll
    for (int i = 0; i < 4; ++i) {
        int idx = tid + i * 256;
        int r = idx >> 5, c = idx & 31;
        float s = 0.f;
        #pragma unroll
        for (int d = 0; d < 64; ++d) s += qs_[r][d] * ks_[c][d];
        cb[r][c] = s * scale;
    }
    __syncthreads();

    if (tid < 32) {
        float m1 = -INFINITY, m2 = -INFINITY;
        for (int n = 0; n < 32; ++n) {
            float v = cb[tid][n];
            if (v > m1) { m2 = m1; m1 = v; }
            else if (v > m2) { m2 = v; }
        }
        unsigned int bits = 1u << tid;
        for (int n = 0; n < 32; ++n)
            if (cb[tid][n] >= m2) bits |= 1u << n;
        maskbits[bid * 32 + tid] = bits;
    }
}

// Proj GEMM via bf16x3 MFMA + bias. R9-proven (XOR swizzle).
__global__ __launch_bounds__(256) void proj_mfma_kernel(
    const short* __restrict__ A, const short* __restrict__ W,
    const float* __restrict__ bias, float* __restrict__ out)
{
    __shared__ short As[128 * 32];
    __shared__ short Bs[64 * 32];
    const int tid = threadIdx.x;
    const int lane = tid & 63;
    const int wave = tid >> 6;
    const int row0 = blockIdx.y * 128;
    const int col0 = blockIdx.x * 64;

    f32x4 acc[2][4];
    const f32x4 zero = {0.f, 0.f, 0.f, 0.f};
    #pragma unroll
    for (int i = 0; i < 2; ++i)
        #pragma unroll
        for (int j = 0; j < 4; ++j) acc[i][j] = zero;

    const int ldr = lane >> 2;
    const int lko = (((lane & 3) ^ ((lane >> 3) & 3))) * 8;
    const int rsl = ((lane >> 4) ^ ((lane >> 1) & 3)) * 8;

    for (int kt = 0; kt < 96; ++kt) {
        const int seg = kt >> 5;
        const int kk = (kt & 31) << 5;
        const int ka0 = kk + (seg == 2 ? 1024 : 0);
        const int kw0 = kk + (seg == 1 ? 1024 : 0);
        #pragma unroll
        for (int i = 0; i < 2; ++i) {
            const int chunk = wave * 2 + i;
            const short* gA = A + (size_t)(row0 + chunk * 16 + ldr) * 2048 + ka0 + lko;
            async_copy16(gA, (char*)As + chunk * 1024);
        }
        {
            const short* gB = W + (size_t)(col0 + wave * 16 + ldr) * 2048 + kw0 + lko;
            async_copy16(gB, (char*)Bs + wave * 1024);
        }
        __syncthreads();
        bf16x8 af[2], bfr[4];
        #pragma unroll
        for (int mi = 0; mi < 2; ++mi)
            af[mi] = *(const bf16x8*)(As + (wave * 32 + mi * 16 + (lane & 15)) * 32 + rsl);
        #pragma unroll
        for (int ni = 0; ni < 4; ++ni)
            bfr[ni] = *(const bf16x8*)(Bs + (ni * 16 + (lane & 15)) * 32 + rsl);
        #pragma unroll
        for (int mi = 0; mi < 2; ++mi)
            #pragma unroll
            for (int ni = 0; ni < 4; ++ni)
                acc[mi][ni] = __builtin_amdgcn_mfma_f32_16x16x32_bf16(af[mi], bfr[ni], acc[mi][ni], 0, 0, 0);
        __syncthreads();
    }

    #pragma unroll
    for (int ni = 0; ni < 4; ++ni) {
        int gc = col0 + ni * 16 + (lane & 15);
        float bv = bias[gc];
        #pragma unroll
        for (int mi = 0; mi < 2; ++mi) {
            int gr0 = row0 + wave * 32 + mi * 16 + (lane >> 4) * 4;
            #pragma unroll
            for (int r = 0; r < 4; ++r)
                out[(size_t)(gr0 + r) * 1024 + gc] = acc[mi][ni][r] + bv;
        }
    }
}

// ---------------------------------------------------------------------------
// Sparse block attention on MFMA — ROUND-6 PROVEN FORM (inline f16 conversion
// staging; the conversion overlaps MFMA/latency and is effectively free).
// fp32 q/k/v inputs (q pre-scaled). Output: bf16 hi|lo split [4096][2048].
// ---------------------------------------------------------------------------
__global__ __launch_bounds__(256) void sparse_attn_mfma_kernel(
    const float* __restrict__ qf, const float* __restrict__ kf,
    const float* __restrict__ vf, const unsigned int* __restrict__ maskbits,
    short* __restrict__ aout)
{
    __shared__ f16 Qh[64 * LSTR], Ql[64 * LSTR];
    __shared__ f16 Kh[64 * LSTR], Kl[64 * LSTR];
    __shared__ f16 Vt[64 * LSTR];            // Vt[d][kk]
    __shared__ f16 Pb[64 * LSTR];            // P[q][kk], wave-private rows

    const int m  = blockIdx.x & 31;
    const int bh = blockIdx.x >> 5;
    const int b  = bh >> 4, h = bh & 15;
    const int tid = threadIdx.x;
    const int lane = tid & 63;
    const int wave = tid >> 6;
    const f32x4 zero = {0.f, 0.f, 0.f, 0.f};

    // ---- stage Q (once): split f32 -> f16 hi|lo
    {
        const int r = tid >> 2, c0 = (tid & 3) * 16;
        const float* src = qf + ((size_t)bh * NN + m * 64 + r) * HD64 + c0;
        #pragma unroll
        for (int j = 0; j < 16; j += 8) {
            f16x8 hv, lv;
            #pragma unroll
            for (int u = 0; u < 8; u += 4) {
                float4 v4 = *(const float4*)(src + j + u);
                float vv[4] = {v4.x, v4.y, v4.z, v4.w};
                #pragma unroll
                for (int w = 0; w < 4; ++w) {
                    f16 hh = (f16)vv[w];
                    hv[u + w] = hh;
                    lv[u + w] = (f16)(vv[w] - (float)hh);
                }
            }
            *(f16x8*)(Qh + r * LSTR + c0 + j) = hv;
            *(f16x8*)(Ql + r * LSTR + c0 + j) = lv;
        }
    }
    __syncthreads();

    const unsigned int mask = maskbits[bh * 32 + m];
    f32x4 s_acc[4], o_acc[4];
    float macc[4], lacc[4];
    #pragma unroll
    for (int r = 0; r < 4; ++r) { macc[r] = -INFINITY; lacc[r] = 0.f; }
    #pragma unroll
    for (int t = 0; t < 4; ++t) o_acc[t] = zero;

    const int arow = wave * 16 + (lane & 15);
    const int kofs = (lane >> 4) * 8;

    for (int nb = 0; nb < 32; ++nb) {
        if (!((mask >> nb) & 1u)) continue;       // uniform across block
        __syncthreads();

        // stage K split + V transposed (inline conversion)
        {
            const int r = tid >> 2, c0 = (tid & 3) * 16;
            const float* srck = kf + ((size_t)bh * NN + nb * 64 + r) * HD64 + c0;
            #pragma unroll
            for (int j = 0; j < 16; j += 8) {
                f16x8 hv, lv;
                #pragma unroll
                for (int u = 0; u < 8; u += 4) {
                    float4 v4 = *(const float4*)(srck + j + u);
                    float vv[4] = {v4.x, v4.y, v4.z, v4.w};
                    #pragma unroll
                    for (int w = 0; w < 4; ++w) {
                        f16 hh = (f16)vv[w];
                        hv[u + w] = hh;
                        lv[u + w] = (f16)(vv[w] - (float)hh);
                    }
                }
                *(f16x8*)(Kh + r * LSTR + c0 + j) = hv;
                *(f16x8*)(Kl + r * LSTR + c0 + j) = lv;
            }
            const int d = tid >> 2, kk0 = (tid & 3) * 16;
            const float* srcv = vf + ((size_t)bh * NN + nb * 64 + kk0) * HD64 + d;
            #pragma unroll
            for (int j = 0; j < 16; j += 8) {
                f16x8 tv;
                #pragma unroll
                for (int u = 0; u < 8; ++u) tv[u] = (f16)srcv[(size_t)(j + u) * 64];
                *(f16x8*)(Vt + d * LSTR + kk0 + j) = tv;
            }
        }
        __syncthreads();

        // ---- QK^T: f16x3 emulation
        #pragma unroll
        for (int t = 0; t < 4; ++t) s_acc[t] = zero;
        #pragma unroll
        for (int c = 0; c < 2; ++c) {
            f16x8 ah = *(const f16x8*)(Qh + arow * LSTR + c * 32 + kofs);
            f16x8 al = *(const f16x8*)(Ql + arow * LSTR + c * 32 + kofs);
            #pragma unroll
            for (int t = 0; t < 4; ++t) {
                f16x8 bh_ = *(const f16x8*)(Kh + (t * 16 + (lane & 15)) * LSTR + c * 32 + kofs);
                f16x8 bl_ = *(const f16x8*)(Kl + (t * 16 + (lane & 15)) * LSTR + c * 32 + kofs);
                s_acc[t] = __builtin_amdgcn_mfma_f32_16x16x32_f16(ah, bh_, s_acc[t], 0, 0, 0);
                s_acc[t] = __builtin_amdgcn_mfma_f32_16x16x32_f16(ah, bl_, s_acc[t], 0, 0, 0);
                s_acc[t] = __builtin_amdgcn_mfma_f32_16x16x32_f16(al, bh_, s_acc[t], 0, 0, 0);
            }
        }

        // ---- online softmax
        float alpha[4], psum[4];
        #pragma unroll
        for (int r = 0; r < 4; ++r) {
            float v0 = fmaxf(fmaxf(s_acc[0][r], s_acc[1][r]), fmaxf(s_acc[2][r], s_acc[3][r]));
            #pragma unroll
            for (int off = 1; off < 16; off <<= 1)
                v0 = fmaxf(v0, __shfl_xor(v0, off));
            float mnew = fmaxf(macc[r], v0);
            alpha[r] = expf(macc[r] - mnew);
            macc[r] = mnew;
            psum[r] = 0.f;
        }
        #pragma unroll
        for (int t = 0; t < 4; ++t) {
            #pragma unroll
            for (int r = 0; r < 4; ++r) {
                float p = expf(s_acc[t][r] - macc[r]);
                psum[r] += p;
                Pb[(wave * 16 + (lane >> 4) * 4 + r) * LSTR + t * 16 + (lane & 15)] = (f16)p;
            }
        }
        #pragma unroll
        for (int r = 0; r < 4; ++r) {
            float v0 = psum[r];
            #pragma unroll
            for (int off = 1; off < 16; off <<= 1) v0 += __shfl_xor(v0, off);
            lacc[r] = lacc[r] * alpha[r] + v0;
            #pragma unroll
            for (int t = 0; t < 4; ++t) o_acc[t][r] *= alpha[r];
        }
        __syncthreads();

        // ---- PV
        #pragma unroll
        for (int c = 0; c < 2; ++c) {
            f16x8 af = *(const f16x8*)(Pb + arow * LSTR + c * 32 + kofs);
            #pragma unroll
            for (int t = 0; t < 4; ++t) {
                f16x8 bf = *(const f16x8*)(Vt + (t * 16 + (lane & 15)) * LSTR + c * 32 + kofs);
                o_acc[t] = __builtin_amdgcn_mfma_f32_16x16x32_f16(af, bf, o_acc[t], 0, 0, 0);
            }
        }
    }

    // ---- epilogue: normalize, split bf16 hi|lo, scatter
    float inv[4];
    #pragma unroll
    for (int r = 0; r < 4; ++r) inv[r] = (lacc[r] > 0.f) ? (1.f / lacc[r]) : 0.f;
    #pragma unroll
    for (int t = 0; t < 4; ++t) {
        int gc = h * 64 + t * 16 + (lane & 15);
        #pragma unroll
        for (int r = 0; r < 4; ++r) {
            int grow = b * NN + m * 64 + wave * 16 + (lane >> 4) * 4 + r;
            float v = o_acc[t][r] * inv[r];
            unsigned short hh = bf16_hi(v);
            unsigned short ll = bf16_hi(v - bf16_val(hh));
            aout[(size_t)grow * 2048 + gc] = (short)hh;
            aout[(size_t)grow * 2048 + 1024 + gc] = (short)ll;
        }
    }
}

// ===========================================================================
// FALLBACK KERNELS (round-2 proven fp32 path)
// ===========================================================================

__global__ __launch_bounds__(256) void block_mean_kernel(
    const float* __restrict__ qf, const float* __restrict__ kf,
    float* __restrict__ qbf, float* __restrict__ kbf)
{
    int idx = blockIdx.x * 256 + threadIdx.x;
    const float* src = (idx < 65536) ? qf : kf;
    float* dst       = (idx < 65536) ? qbf : kbf;
    int e = idx & 65535;
    int d = e & 63;
    int r = e >> 6;
    size_t base = (size_t)r * 4096 + d;
    float s = 0.f;
    #pragma unroll
    for (int i = 0; i < 64; ++i) s += src[base + (size_t)i * 64];
    dst[e] = s * (1.f / 64.f);
}

__global__ __launch_bounds__(256) void qkv_gemm_fb(
    const float* __restrict__ x, const float* __restrict__ w,
    float* __restrict__ qf, float* __restrict__ kf, float* __restrict__ vf)
{
    __shared__ float As[64][33];
    __shared__ float Bs[64][33];
    const int tid = threadIdx.x;
    const int row0 = blockIdx.y * 64;
    const int col0 = blockIdx.x * 64;
    const int ty = tid >> 4, tx = tid & 15;

    float acc[4][4] = {};
    for (int k0 = 0; k0 < 1024; k0 += 32) {
        #pragma unroll
        for (int i = 0; i < 8; ++i) {
            int e = tid + i * 256;
            int r = e >> 5, c = e & 31;
            As[r][c] = x[(size_t)(row0 + r) * 1024 + k0 + c];
            Bs[r][c] = w[(size_t)(col0 + r) * 1024 + k0 + c];
        }
        __syncthreads();
        #pragma unroll
        for (int kk = 0; kk < 32; ++kk) {
            float a[4], b[4];
            #pragma unroll
            for (int i = 0; i < 4; ++i) a[i] = As[ty * 4 + i][kk];
            #pragma unroll
            for (int j = 0; j < 4; ++j) b[j] = Bs[tx * 4 + j][kk];
            #pragma unroll
            for (int i = 0; i < 4; ++i)
                #pragma unroll
                for (int j = 0; j < 4; ++j)
                    acc[i][j] += a[i] * b[j];
        }
        __syncthreads();
    }

    const int tsel = col0 >> 10;
    const int h    = (col0 & 1023) >> 6;
    float* dstbuf = (tsel == 0) ? qf : (tsel == 1) ? kf : vf;
    #pragma unroll
    for (int i = 0; i < 4; ++i) {
        int row = row0 + ty * 4 + i;
        int b   = row >> 11, n = row & 2047;
        size_t rb = ((size_t)(b * HH + h) * NN + n) * HD64;
        #pragma unroll
        for (int j = 0; j < 4; ++j)
            dstbuf[rb + tx * 4 + j] = acc[i][j];
    }
}

__global__ __launch_bounds__(256) void proj_gemm_fb(
    const float* __restrict__ attn, const float* __restrict__ w,
    const float* __restrict__ bias, float* __restrict__ out)
{
    __shared__ float As[64][33];
    __shared__ float Bs[64][33];
    const int tid = threadIdx.x;
    const int row0 = blockIdx.y * 64;
    const int col0 = blockIdx.x * 64;
    const int ty = tid >> 4, tx = tid & 15;

    float acc[4][4] = {};
    for (int k0 = 0; k0 < 1024; k0 += 32) {
        #pragma unroll
        for (int i = 0; i < 8; ++i) {
            int e = tid + i * 256;
            int r = e >> 5, c = e & 31;
            As[r][c] = attn[(size_t)(row0 + r) * 1024 + k0 + c];
            Bs[r][c] = w[(size_t)(col0 + r) * 1024 + k0 + c];
        }
        __syncthreads();
        #pragma unroll
        for (int kk = 0; kk < 32; ++kk) {
            float a[4], b[4];
            #pragma unroll
            for (int i = 0; i < 4; ++i) a[i] = As[ty * 4 + i][kk];
            #pragma unroll
            for (int j = 0; j < 4; ++j) b[j] = Bs[tx * 4 + j][kk];
            #pragma unroll
            for (int i = 0; i < 4; ++i)
                #pragma unroll
                for (int j = 0; j < 4; ++j)
                    acc[i][j] += a[i] * b[j];
        }
        __syncthreads();
    }

    #pragma unroll
    for (int j = 0; j < 4; ++j) {
        int col = col0 + tx * 4 + j;
        float bv = bias[col];
        #pragma unroll
        for (int i = 0; i < 4; ++i) {
            int row = row0 + ty * 4 + i;
            out[(size_t)row * 1024 + col] = acc[i][j] + bv;
        }
    }
}

__global__ __launch_bounds__(256) void sparse_attn_fb(
    const float* __restrict__ qf, const float* __restrict__ kf,
    const float* __restrict__ vf, const unsigned int* __restrict__ maskbits,
    float* __restrict__ attnf)
{
    __shared__ float kbuf[64][64];
    __shared__ float vbuf[64][64];
    __shared__ float sbuf[64][65];
    const int m  = blockIdx.x & 31;
    const int bh = blockIdx.x >> 5;
    const int b  = bh >> 4, h = bh & 15;
    const int t  = threadIdx.x;
    const int qr = t >> 2;
    const int dg = t & 3;
    const int d0 = dg * 16;

    float qreg[16];
    {
        const float* qp = qf + ((size_t)bh * NN + m * 64 + qr) * HD64 + d0;
        #pragma unroll
        for (int j = 0; j < 16; j += 4) {
            float4 v = *(const float4*)(qp + j);
            qreg[j] = v.x; qreg[j+1] = v.y; qreg[j+2] = v.z; qreg[j+3] = v.w;
        }
    }

    const unsigned int mask = maskbits[bh * 32 + m];
    float macc = -INFINITY, lacc = 0.f;
    float oacc[16];
    #pragma unroll
    for (int j = 0; j < 16; ++j) oacc[j] = 0.f;

    for (int nb = 0; nb < 32; ++nb) {
        if (!((mask >> nb) & 1u)) continue;
        __syncthreads();
        {
            const float* gk = kf + ((size_t)bh * NN + nb * 64) * HD64;
            const float* gv = vf + ((size_t)bh * NN + nb * 64) * HD64;
            #pragma unroll
            for (int i = 0; i < 4; ++i) {
                async_copy16(gk + t * 4 + i * 1024, (char*)kbuf + t * 16 + i * 4096);
                async_copy16(gv + t * 4 + i * 1024, (char*)vbuf + t * 16 + i * 4096);
            }
        }
        __syncthreads();

        float bmax = -INFINITY;
        for (int kk = 0; kk < 64; ++kk) {
            float s = 0.f;
            #pragma unroll
            for (int j = 0; j < 16; ++j) s += qreg[j] * kbuf[kk][d0 + j];
            s += __shfl_xor(s, 1);
            s += __shfl_xor(s, 2);
            s *= SCALE_F;
            if (dg == 0) sbuf[qr][kk] = s;
            bmax = fmaxf(bmax, s);
        }
        float mnew  = fmaxf(macc, bmax);
        float alpha = expf(macc - mnew);
        lacc *= alpha;
        #pragma unroll
        for (int j = 0; j < 16; ++j) oacc[j] *= alpha;
        for (int kk = 0; kk < 64; ++kk) {
            float p = expf(sbuf[qr][kk] - mnew);
            lacc += p;
            #pragma unroll
            for (int j = 0; j < 16; ++j) oacc[j] += p * vbuf[kk][d0 + j];
        }
        macc = mnew;
    }

    float inv = (lacc > 0.f) ? (1.f / lacc) : 0.f;
    size_t orow = ((size_t)(b * NN + m * 64 + qr)) * DIMD + h * 64 + d0;
    #pragma unroll
    for (int j = 0; j < 16; ++j) attnf[orow + j] = oacc[j] * inv;
}

// ---------------------------------------------------------------------------
extern "C" void kernel_launch(void* const* d_in, const int* in_sizes, int n_in,
                              void* d_out, int out_size, void* d_ws, size_t ws_size,
                              hipStream_t stream)
{
    const float* x      = (const float*)d_in[0];
    const float* qkv_w  = (const float*)d_in[1];
    const float* proj_w = (const float*)d_in[2];
    const float* proj_b = (const float*)d_in[3];
    float* out = (float*)d_out;

    // Carve (80,220,160 B, proven):
    //   C/D/E 3x16.8M: q/k/v fp32 | qbf/kbf 512K | mask 4K
    //   A 16.8M: Axs (x-split; reused as attention output)
    //   B 12.6M: Wqs (qkv_w split; head 4.2M reused for proj_w split)
    float* qC = (float*)d_ws;
    float* kD = qC + 4194304;
    float* vE = kD + 4194304;
    float* qbf = vE + 4194304;
    float* kbf = qbf + 65536;
    unsigned int* maskb = (unsigned int*)(kbf + 65536);
    short* Axs = (short*)(maskb + 1024);
    short* Wqs = Axs + (size_t)4096 * 2048;
    const size_t need_fast = (size_t)((char*)(Wqs + (size_t)3072 * 2048) - (char*)d_ws);

    if (ws_size >= need_fast) {
        split_in_fused_kernel<<<7168, 256, 0, stream>>>(x, Axs, qkv_w, Wqs);
        qkv_mfma_kernel<<<dim3(24, 32), 256, 0, stream>>>(Axs, Wqs, qC, kD, vE, qbf, kbf);
        scores_splitw_kernel<<<1056, 256, 0, stream>>>(qbf, kbf, maskb, 1.0f, proj_w, Wqs);
        sparse_attn_mfma_kernel<<<1024, 256, 0, stream>>>(qC, kD, vE, maskb, Axs);
        proj_mfma_kernel<<<dim3(16, 32), 256, 0, stream>>>(Axs, Wqs, proj_b, out);
    } else {
        float* qf2  = (float*)d_ws;
        float* kf2  = qf2 + 4194304;
        float* vf2  = kf2 + 4194304;
        float* qbf2 = vf2 + 4194304;
        float* kbf2 = qbf2 + 65536;
        unsigned int* maskb2 = (unsigned int*)(kbf2 + 65536);
        float* attnf = (float*)(maskb2 + 1024);
        qkv_gemm_fb<<<dim3(48, 64), 256, 0, stream>>>(x, qkv_w, qf2, kf2, vf2);
        block_mean_kernel<<<512, 256, 0, stream>>>(qf2, kf2, qbf2, kbf2);
        scores_splitw_kernel<<<32, 256, 0, stream>>>(qbf2, kbf2, maskb2, SCALE_F,
                                                     (const float*)nullptr, (short*)nullptr);
        sparse_attn_fb<<<1024, 256, 0, stream>>>(qf2, kf2, vf2, maskb2, attnf);
        proj_gemm_fb<<<dim3(16, 64), 256, 0, stream>>>(attnf, proj_w, proj_b, out);
    }
}